// Round 5
// baseline (164.138 us; speedup 1.0000x reference)
//
#include <hip/hip_runtime.h>
#include <math.h>

typedef __attribute__((ext_vector_type(8)))  short short8;
typedef __attribute__((ext_vector_type(16))) float f32x16;

#define NPLANE 48
#define H 512
#define W 512
#define TH 21
#define OH 492
#define OW 492
#define EPSF 1e-8f

#define STRIDE 168   // LDS row stride in shorts
#define SEG_ROWS 84  // 64 output rows + 20 halo

// d_ws layout (bytes) — ~4.13 MB:
//   [0)        B_corr : 48 * 21 * 4 * 512 bf16 (frag-swizzled)
//   [4128768)  B_ones : 4 * 512 bf16
#define BONES_HOFF (4128768u / 2)

__device__ inline unsigned short f2bf(float f) {
    unsigned u = __float_as_uint(f);
    return (unsigned short)((u + 0x7FFFu + ((u >> 16) & 1u)) >> 16);
}
__device__ inline float bf2f(unsigned s) {
    return __uint_as_float(s << 16);
}

#if defined(__has_builtin)
#if __has_builtin(__builtin_amdgcn_cvt_pk_bf16_f32)
#define HAVE_CVT_PK_BF16 1
#endif
#endif

#ifdef HAVE_CVT_PK_BF16
typedef __attribute__((ext_vector_type(2))) __bf16 bf16x2;
__device__ inline unsigned pack2bf(float a, float b) {
    bf16x2 r = __builtin_amdgcn_cvt_pk_bf16_f32(a, b);
    return *(unsigned*)&r;
}
#else
__device__ inline unsigned pack2bf(float a, float b) {
    return (unsigned)f2bf(a) | ((unsigned)f2bf(b) << 16);
}
#endif

// ---------------------------------------------------------------------------
// K0: template z-norm (/441 folded) -> Toeplitz B fragments (frag-swizzled:
// main kernel's B load is lane*8 contiguous bf16).
// B[k][n] = t_hat[u][16s + k - n], k = (lane>>5)*8 + j, n = lane&31.
// ---------------------------------------------------------------------------
__global__ void build_b_kernel(const float* __restrict__ tpl,
                               unsigned short* __restrict__ ws16) {
    __shared__ float sm[2];
    const int plane = blockIdx.x;
    const float* t = tpl + plane * 441;
    const int tid = threadIdx.x;
    if (tid < 64) {
        float s = 0.f, s2 = 0.f;
        for (int k = tid; k < 441; k += 64) {
            float x = t[k];
            s += x; s2 += x * x;
        }
#pragma unroll
        for (int o = 32; o >= 1; o >>= 1) {
            s  += __shfl_down(s, o);
            s2 += __shfl_down(s2, o);
        }
        if (tid == 0) {
            float mean = s / 441.f;
            float var = fmaxf(s2 / 441.f - mean * mean, 0.f);
            sm[0] = mean;
            sm[1] = 1.f / ((sqrtf(var) + EPSF) * 441.f);
        }
    }
    __syncthreads();
    const float mean = sm[0], scale = sm[1];

    unsigned short* bc = ws16 + (size_t)plane * 43008;
    for (int i = tid; i < 43008; i += 256) {
        int j = i & 7, lane = (i >> 3) & 63, s = (i >> 9) & 3, u = i >> 11;
        int k = ((lane >> 5) << 3) + j, n = lane & 31;
        int v = 16 * s + k - n;
        float val = (v >= 0 && v < TH) ? (t[u * 21 + v] - mean) * scale : 0.f;
        bc[i] = f2bf(val);
    }
    if (plane == 0) {
        unsigned short* bo = ws16 + BONES_HOFF;
        const unsigned short one = f2bf(1.f);
        for (int i = tid; i < 2048; i += 256) {
            int j = i & 7, lane = (i >> 3) & 63, s = (i >> 9) & 3;
            int k = ((lane >> 5) << 3) + j, n = lane & 31;
            int v = 16 * s + k - n;
            bo[i] = (v >= 0 && v < TH) ? one : (unsigned short)0;
        }
    }
}

// ---------------------------------------------------------------------------
// K1: fully fused NCC. Block = 64x128 outputs, 4 waves x two 32x32 MFMA tiles.
// Phases: [stage 84x160 fp32->bf16 LDS] -> bar ->
//         [corr K-loop: fully unrolled 21u x (6 ds_read_b128 + 8 MFMA)] -> bar
//         [ONE box pass: 80 col-pair workers, S->vbuf, Q->seg in-place] -> bar
//         [aS+aQ ones-Toeplitz MFMAs -> native rsqrt-normalize -> store]
// In-place Q is safe: each worker owns its column pair exclusively and reads
// seg[y] before overwriting it; rows 64..83 keep original data (unused by aQ).
// LDS = (84+64)*168*2 = 49.7 KB -> 3 blocks/CU.
// ---------------------------------------------------------------------------
__global__ __launch_bounds__(256, 3) void ncc_fused_kernel(
    const float* __restrict__ in, const unsigned short* __restrict__ ws16,
    float* __restrict__ out) {
    __shared__ short seg[SEG_ROWS * STRIDE];
    __shared__ short vbuf[64 * STRIDE];

    const int plane = blockIdx.z;
    const int x0 = blockIdx.x * 128;
    const int y0 = blockIdx.y * 64;
    const int tid = threadIdx.x;
    const int lane = tid & 63;
    const int tr = (tid >> 6) & 1;   // tile-row of this wave
    const int tc = tid >> 7;         // tile-col pair of this wave
    const float* src = in + (size_t)plane * H * W;

    // ---- stage 84x160 fp32 -> bf16 into LDS ----
    for (int i = tid; i < SEG_ROWS * 20; i += 256) {
        int row = i / 20, s8 = i - row * 20;
        int gy = y0 + row, gx = x0 + s8 * 8;
        if (gy < H && gx + 7 < W) {
            float4 a = *(const float4*)(src + gy * W + gx);
            float4 b = *(const float4*)(src + gy * W + gx + 4);
            int4 p;
            p.x = (int)pack2bf(a.x, a.y);
            p.y = (int)pack2bf(a.z, a.w);
            p.z = (int)pack2bf(b.x, b.y);
            p.w = (int)pack2bf(b.z, b.w);
            *(int4*)&seg[row * STRIDE + s8 * 8] = p;
        } else {
            short8 val;
#pragma unroll
            for (int e = 0; e < 8; ++e) {
                float xv = (gy < H && gx + e < W) ? src[gy * W + gx + e] : 0.f;
                val[e] = (short)f2bf(xv);
            }
            *(short8*)&seg[row * STRIDE + s8 * 8] = val;
        }
    }
    __syncthreads();

    const int m = lane & 31;
    const int half = lane >> 5;
    const int abase = (tr * 32 + m) * STRIDE + tc * 64 + half * 8;
    const unsigned short* bc = ws16 + (size_t)plane * 43008 + lane * 8;

    // bones fragments early (latency overlap with K-loop).
    const unsigned short* bo16 = ws16 + BONES_HOFF + lane * 8;
    short8 bones[4];
#pragma unroll
    for (int s = 0; s < 4; ++s)
        bones[s] = *(const short8*)(bo16 + s * 512);

    f32x16 acc[2];
#pragma unroll
    for (int t = 0; t < 2; ++t)
#pragma unroll
        for (int e = 0; e < 16; ++e) acc[t][e] = 0.f;

    // Fully unrolled K-loop: compiler renames regs (no dbuf copies) and
    // schedules the independent global/LDS loads ahead of use.
#pragma unroll
    for (int u = 0; u < TH; ++u) {
        short8 bf[4];
#pragma unroll
        for (int s = 0; s < 4; ++s)
            bf[s] = *(const short8*)(bc + (u * 4 + s) * 512);
        short8 af[6];
#pragma unroll
        for (int g = 0; g < 6; ++g)
            af[g] = *(const short8*)&seg[abase + u * STRIDE + g * 16];
#pragma unroll
        for (int t = 0; t < 2; ++t)
#pragma unroll
            for (int s = 0; s < 4; ++s)
                acc[t] = __builtin_amdgcn_mfma_f32_32x32x16_bf16(
                    af[2 * t + s], bf[s], acc[t], 0, 0, 0);
    }
    __syncthreads();  // box pass overwrites seg rows 0..63: all corr reads done

    // ---- single box pass: vertical 21-sums, S -> vbuf, Q -> seg in-place ----
    if (tid < 80) {
        const int c2 = tid * 2;
        float s0 = 0.f, s1 = 0.f, q0 = 0.f, q1 = 0.f;
#pragma unroll
        for (int r = 0; r < 20; ++r) {
            unsigned p = *(const unsigned*)&seg[r * STRIDE + c2];
            float a = bf2f(p & 0xffffu), b = bf2f(p >> 16);
            s0 += a; s1 += b;
            q0 = fmaf(a, a, q0); q1 = fmaf(b, b, q1);
        }
        for (int y = 0; y < 64; ++y) {
            unsigned p = *(const unsigned*)&seg[(y + 20) * STRIDE + c2];
            float a = bf2f(p & 0xffffu), b = bf2f(p >> 16);
            s0 += a; s1 += b;
            q0 = fmaf(a, a, q0); q1 = fmaf(b, b, q1);
            *(unsigned*)&vbuf[y * STRIDE + c2] = pack2bf(s0, s1);
            unsigned o = *(const unsigned*)&seg[y * STRIDE + c2];  // read old
            float c = bf2f(o & 0xffffu), d = bf2f(o >> 16);
            *(unsigned*)&seg[y * STRIDE + c2] = pack2bf(q0, q1);   // then write
            s0 -= c; s1 -= d;
            q0 = fmaf(-c, c, q0); q1 = fmaf(-d, d, q1);
        }
    }
    __syncthreads();

    // ---- aS (from vbuf) + aQ (from seg) + normalize + store ----
    const float invn = 1.f / 441.f;
    float* outp = out + (size_t)plane * OH * OW;
#pragma unroll
    for (int t = 0; t < 2; ++t) {
        f32x16 aS, aQ;
#pragma unroll
        for (int e = 0; e < 16; ++e) { aS[e] = 0.f; aQ[e] = 0.f; }
#pragma unroll
        for (int s = 0; s < 4; ++s) {
            short8 vf = *(const short8*)&vbuf[abase + (2 * t + s) * 16];
            aS = __builtin_amdgcn_mfma_f32_32x32x16_bf16(vf, bones[s], aS,
                                                         0, 0, 0);
            short8 qf = *(const short8*)&seg[abase + (2 * t + s) * 16];
            aQ = __builtin_amdgcn_mfma_f32_32x32x16_bf16(qf, bones[s], aQ,
                                                         0, 0, 0);
        }
        const int gx = x0 + tc * 64 + t * 32 + (lane & 31);
        if (gx < OW) {
#pragma unroll
            for (int r = 0; r < 16; ++r) {
                int gy = y0 + tr * 32 + (r & 3) + ((r >> 2) << 3) + half * 4;
                if (gy < OH) {
                    float mean = aS[r] * invn;
                    float msq = aQ[r] * invn;
                    float sd =
                        __builtin_amdgcn_sqrtf(msq - mean * mean + EPSF);
                    outp[(size_t)gy * OW + gx] =
                        acc[t][r] * __builtin_amdgcn_rcpf(sd + EPSF);
                }
            }
        }
    }
}

extern "C" void kernel_launch(void* const* d_in, const int* in_sizes, int n_in,
                              void* d_out, int out_size, void* d_ws,
                              size_t ws_size, hipStream_t stream) {
    const float* inputs = (const float*)d_in[0];
    const float* tmpl = (const float*)d_in[1];
    float* out = (float*)d_out;
    unsigned short* ws16 = (unsigned short*)d_ws;

    build_b_kernel<<<NPLANE, 256, 0, stream>>>(tmpl, ws16);
    ncc_fused_kernel<<<dim3(4, 8, NPLANE), 256, 0, stream>>>(inputs, ws16, out);
}